// Round 4
// baseline (186.783 us; speedup 1.0000x reference)
//
#include <hip/hip_runtime.h>
#include <hip/hip_fp16.h>
#include <math.h>

#define IN 8000
#define OC 10
#define NUNIT 1000              // 1000 units x 8 i-rows x 2 (il pairs) -> 16 i
#define VACC_F (64 * OC * 16)   // 10240 floats
#define PART_H (64 * OC * 16)   // 10240 halfs per chunk (20 KB)

// per-unit f16 record: [8 il][10 o][16 d][8 e] (20480 B) then [8 il][64 b][8 e] (8192 B)
#define REC_B   28672
#define REC_H   14336
#define XOFF_B  20480
#define XOFF_H  10240
#define REC_TOTAL_B ((size_t)NUNIT * REC_B)   // 28,672,000

// red reduce area: [64 b][164 f32] = 41,984 B (aliases the staging buffer)
#define SM_BYTES 41984

typedef __fp16 h2 __attribute__((ext_vector_type(2)));
typedef _Float16 half8 __attribute__((ext_vector_type(8)));
typedef float f32x16 __attribute__((ext_vector_type(16)));

__device__ __forceinline__ h2 asb(unsigned int v) { return __builtin_bit_cast(h2, v); }

__device__ __forceinline__ float dot2(h2 a, h2 b, float c) {
#if __has_builtin(__builtin_amdgcn_fdot2)
    return __builtin_amdgcn_fdot2(a, b, c, false);
#else
    return fmaf((float)a[0], (float)b[0], fmaf((float)a[1], (float)b[1], c));
#endif
}

__device__ __forceinline__ unsigned int pk_rn(float a, float b) {
    return __builtin_bit_cast(unsigned int, __float22half2_rn(make_float2(a, b)));
}

#define GLDS16(gp, lp) __builtin_amdgcn_global_load_lds(                      \
    (const __attribute__((address_space(1))) void*)(gp),                      \
    (__attribute__((address_space(3))) void*)(lp), 16, 0, 0)

// ---------------------------------------------------------------------------
// Prep: W (10,8000,16,8) f32 + x (64,8000,8) f32  ->  f16 unit records laid
// out exactly as the pass's LDS buffer, so staging is pure global_load_lds.
// Blocks [0,1250): W. granule = 8 halfs (one d-row); 1,280,000 granules, 4/thr.
// Blocks [1250,1500): x. wave w handles u = (blk-1250)*4+w, lane = b.
// ---------------------------------------------------------------------------
__global__ __launch_bounds__(256) void caps_prep(
    const float* __restrict__ W, const float* __restrict__ x,
    __fp16* __restrict__ rec)
{
    const int t   = threadIdx.x;
    const int blk = blockIdx.x;
    if (blk < 1250) {
        const int gt = blk * 256 + t;
#pragma unroll
        for (int k = 0; k < 4; ++k) {
            int g  = gt + k * 320000;
            int u  = g / 1280;
            int r  = g - u * 1280;
            int il = r / 160;
            int rr = r - il * 160;
            int o  = rr >> 4;
            int d  = rr & 15;
            const float* ip = W + ((size_t)o * IN + (size_t)(u * 8 + il)) * 128 + d * 8;
            float4 f0 = *(const float4*)(ip);
            float4 f1 = *(const float4*)(ip + 4);
            uint4 pk = make_uint4(pk_rn(f0.x, f0.y), pk_rn(f0.z, f0.w),
                                  pk_rn(f1.x, f1.y), pk_rn(f1.z, f1.w));
            *(uint4*)(rec + (size_t)u * REC_H + il * 1280 + o * 128 + d * 8) = pk;
        }
    } else {
        const int u    = (blk - 1250) * 4 + (t >> 6);
        const int lane = t & 63;           // = b
#pragma unroll
        for (int il = 0; il < 8; ++il) {
            const float* ip = x + ((size_t)lane * IN + (size_t)(u * 8 + il)) * 8;
            float4 f0 = *(const float4*)(ip);
            float4 f1 = *(const float4*)(ip + 4);
            uint4 pk = make_uint4(pk_rn(f0.x, f0.y), pk_rn(f0.z, f0.w),
                                  pk_rn(f1.x, f1.y), pk_rn(f1.z, f1.w));
            *(uint4*)(rec + (size_t)u * REC_H + XOFF_H + il * 512 + lane * 8) = pk;
        }
    }
}

// ---------------------------------------------------------------------------
// Kernel A: 256 thr (4 waves = 2 b-halves x 2 i-set halves), ONE unit per
// block (grid = 1000). 42 KB LDS + launch_bounds(256,3) -> 3 blocks/CU
// (12 waves/CU, vs round-3's 8) for latency hiding. Routing accumulator is
// packed f16 (v_pk_fma_f16): only 16 i-terms per block, error ~= the f16
// part-quantization already present. Compute math otherwise = verified R1.
// ---------------------------------------------------------------------------
template<int UNIFORM>
__global__ __launch_bounds__(256, 3) void caps_pass(
    const __fp16* __restrict__ rec, const float* __restrict__ Vacc,
    __fp16* __restrict__ part)
{
    __shared__ __align__(16) unsigned char sm[SM_BYTES];    // staging / red alias
    __shared__ __align__(16) unsigned char zs[16];          // zero slot

    const int t    = threadIdx.x;
    const int w    = t >> 6;
    const int lane = t & 63;
    const int lo   = lane & 31;
    const int hi   = lane >> 5;
    const int bt   = w & 1;            // b-half: b in [bt*32, bt*32+32)
    const int ph   = w >> 1;           // i-set half (0/1)
    const int b    = bt * 32 + lo;

    if (t < 4) ((unsigned int*)zs)[t] = 0u;

    // cached v * log2e as f16 pairs matching this lane's C-row d pattern:
    // vh[o][0..3] = v[d], d = {0,1,2,3,8,9,10,11} + 4*hi
    h2 vh[10][4];
    if (!UNIFORM) {
        const float* vp = Vacc + (size_t)b * (OC * 16);
        const float L2E = 1.44269504f;
#pragma unroll
        for (int o = 0; o < OC; ++o) {
            float4 fa = *(const float4*)(vp + o * 16 + 4 * hi);
            float4 fb = *(const float4*)(vp + o * 16 + 8 + 4 * hi);
            vh[o][0] = asb(pk_rn(fa.x * L2E, fa.y * L2E));
            vh[o][1] = asb(pk_rn(fa.z * L2E, fa.w * L2E));
            vh[o][2] = asb(pk_rn(fb.x * L2E, fb.y * L2E));
            vh[o][3] = asb(pk_rn(fb.z * L2E, fb.w * L2E));
        }
    }

    // UNIFORM accumulator: f32 MFMA C-regs. Routing accumulator: packed f16.
    f32x16 acc[5];
    h2 acch[5][8];
    if (UNIFORM) {
#pragma unroll
        for (int op = 0; op < 5; ++op)
#pragma unroll
            for (int k = 0; k < 16; ++k) acc[op][k] = 0.f;
    } else {
#pragma unroll
        for (int op = 0; op < 5; ++op)
#pragma unroll
            for (int q = 0; q < 8; ++q) acch[op][q] = h2{(__fp16)0.f, (__fp16)0.f};
    }

    f32x16 zc;
#pragma unroll
    for (int k = 0; k < 16; ++k) zc[k] = 0.f;

    const int bid  = blockIdx.x;
    const int grid = gridDim.x;

    // staging: 28 chunks of 1 KiB per unit; wave w issues q = c*4+w
    auto issue = [&](int st) {
        const char* g = (const char*)rec + (size_t)st * REC_B + (size_t)lane * 16;
#pragma unroll
        for (int c = 0; c < 7; ++c) {
            const int q = c * 4 + w;
            GLDS16(g + q * 1024, sm + q * 1024);
        }
    };

    bool first = true;
    for (int st = bid; st < NUNIT; st += grid) {   // grid=1000 -> exactly once
        if (!first) __syncthreads();               // readers done with sm
        issue(st);
        __syncthreads();                           // vmcnt(0) drain: resident
        first = false;

        const unsigned char* buf = sm;

        if (UNIFORM) {
            // dense: 2 i's per MFMA along K (k-group = lane>>5 -> i')
#pragma unroll
            for (int ip = 0; ip < 2; ++ip) {
                const int il0 = ph * 4 + ip * 2;
                half8 xb = *(const half8*)(buf + XOFF_B + (il0 + hi) * 1024 + b * 16);
#pragma unroll
                for (int op = 0; op < 5; ++op) {
                    half8 av = *(const half8*)(buf + (il0 + hi) * 2560 + op * 512 + lo * 16);
                    acc[op] = __builtin_amdgcn_mfma_f32_32x32x16_f16(av, xb, acc[op], 0, 0, 0);
                }
            }
        } else {
#pragma unroll 1
            for (int u = 0; u < 4; ++u) {
                const int il = ph * 4 + u;
                // B operand: lanes<32 real x rows (k=e), lanes>=32 -> zero slot
                const unsigned char* xaddr = (lane < 32)
                    ? (buf + XOFF_B + il * 1024 + b * 16)
                    : (const unsigned char*)zs;
                half8 xb = *(const half8*)xaddr;

                h2 uh2[5][8];
                float lgf[10];
#pragma unroll
                for (int op = 0; op < 5; ++op) {
                    // A: lanes>=32 duplicate lanes 0-31 (k>=8 don't-care, B=0 there)
                    half8 av = *(const half8*)(buf + il * 2560 + op * 512 + lo * 16);
                    f32x16 C = __builtin_amdgcn_mfma_f32_32x32x16_f16(av, xb, zc, 0, 0, 0);
#pragma unroll
                    for (int q = 0; q < 8; ++q)
                        uh2[op][q] = __builtin_amdgcn_cvt_pkrtz(C[2 * q], C[2 * q + 1]);
                    float l0 = 0.f, l1 = 0.f;
#pragma unroll
                    for (int qq = 0; qq < 4; ++qq) {
                        l0 = dot2(uh2[op][qq],     vh[op * 2][qq],     l0);
                        l1 = dot2(uh2[op][4 + qq], vh[op * 2 + 1][qq], l1);
                    }
                    lgf[op * 2]     = l0;
                    lgf[op * 2 + 1] = l1;
                }
                // d-reduce: partner lane (l^32) holds the other 8 d's of each o
#pragma unroll
                for (int pp = 0; pp < 5; ++pp) {
                    h2 lp = asb(pk_rn(lgf[2 * pp], lgf[2 * pp + 1]));
                    int ob = __shfl_xor(__builtin_bit_cast(int, lp), 32);
                    h2 s2 = lp + __builtin_bit_cast(h2, ob);
                    lgf[2 * pp]     = (float)s2[0];
                    lgf[2 * pp + 1] = (float)s2[1];
                }
                // softmax over 10 o (logits pre-scaled by log2e -> exp2)
                float mx = lgf[0];
#pragma unroll
                for (int o = 1; o < OC; ++o) mx = fmaxf(mx, lgf[o]);
                float pe[10];
                float se = 0.f;
#pragma unroll
                for (int o = 0; o < OC; ++o) {
                    pe[o] = __builtin_amdgcn_exp2f(lgf[o] - mx);
                    se += pe[o];
                }
                float rs = __builtin_amdgcn_rcpf(se);
                // weighted accumulate, packed f16: acch += c ⊙ uh2 (pk_fma)
#pragma unroll
                for (int op = 0; op < 5; ++op) {
                    float c0 = pe[op * 2] * rs;
                    float c1 = pe[op * 2 + 1] * rs;
                    h2 ch0 = __builtin_amdgcn_cvt_pkrtz(c0, c0);
                    h2 ch1 = __builtin_amdgcn_cvt_pkrtz(c1, c1);
#pragma unroll
                    for (int q = 0; q < 4; ++q) {
                        acch[op][q]     = ch0 * uh2[op][q]     + acch[op][q];
                        acch[op][4 + q] = ch1 * uh2[op][4 + q] + acch[op][4 + q];
                    }
                }
            }
        }
    }

    // block reduce across the two ph-waves per bt; red aliases sm: [64][164] f32
    float* red = (float*)sm;
#pragma unroll 1
    for (int phase = 0; phase < 2; ++phase) {
        __syncthreads();
        if (ph == phase) {
#pragma unroll
            for (int op = 0; op < 5; ++op)
#pragma unroll
                for (int q = 0; q < 8; ++q) {
                    const int o  = op * 2 + (q >> 2);
                    const int d0 = 2 * (q & 1) + 8 * ((q >> 1) & 1) + 4 * hi;
                    float e0, e1;
                    if (UNIFORM) { e0 = acc[op][2 * q]; e1 = acc[op][2 * q + 1]; }
                    else         { e0 = (float)acch[op][q][0]; e1 = (float)acch[op][q][1]; }
                    float* p = &red[(size_t)b * 164 + o * 16 + d0];
                    if (phase == 0) {
                        *(float2*)p = make_float2(e0, e1);
                    } else {
                        float2 v2 = *(const float2*)p;
                        v2.x += e0; v2.y += e1;
                        *(float2*)p = v2;
                    }
                }
        }
    }
    __syncthreads();
    // flush partial as f16, transposed: part[bo][chunk][16]
    unsigned int* dst = (unsigned int*)part;
    for (int q = t; q < PART_H / 2; q += 256) {
        int bo = q >> 3;
        int u8 = q & 7;
        int bb = bo / 10;
        int oo = bo - bb * 10;
        float2 v2 = *(const float2*)&red[(size_t)bb * 164 + oo * 16 + u8 * 2];
        dst[(size_t)(bo * grid + bid) * 8 + u8] = pk_rn(v2.x, v2.y);
    }
}

// ---------------------------------------------------------------------------
// Kernel B: one block per (b,o). part is [bo][chunk][16] f16 -> coalesced.
// mode 0: Vacc =, mode 1: Vacc +=, mode 2: out =.
// ---------------------------------------------------------------------------
__global__ __launch_bounds__(256) void caps_reduce(
    const __fp16* __restrict__ part, float* __restrict__ Vacc,
    float* __restrict__ out, int nchunk, int mode, float scale)
{
    const int bo = blockIdx.x;      // b*10+o, [0,640)
    const int t  = threadIdx.x;
    const int d2 = t & 3;           // 4 d's: 4*d2..4*d2+3
    const int s  = t >> 2;          // 64 chunk slices

    const unsigned int* p32 = (const unsigned int*)part + (size_t)bo * nchunk * 8;
    float4 a = make_float4(0.f, 0.f, 0.f, 0.f);
    for (int c = s; c < nchunk; c += 64) {
        uint2 v = *(const uint2*)(p32 + (size_t)c * 8 + d2 * 2);
        h2 lov = asb(v.x), hiv = asb(v.y);
        a.x += (float)lov[0]; a.y += (float)lov[1];
        a.z += (float)hiv[0]; a.w += (float)hiv[1];
    }
#pragma unroll
    for (int m = 4; m <= 32; m <<= 1) {
        a.x += __shfl_xor(a.x, m); a.y += __shfl_xor(a.y, m);
        a.z += __shfl_xor(a.z, m); a.w += __shfl_xor(a.w, m);
    }
    __shared__ float red[4][16];
    const int wv = t >> 6;
    if ((t & 63) < 4) {
        red[wv][d2 * 4 + 0] = a.x; red[wv][d2 * 4 + 1] = a.y;
        red[wv][d2 * 4 + 2] = a.z; red[wv][d2 * 4 + 3] = a.w;
    }
    __syncthreads();
    if (t < 16) {
        float sv = (red[0][t] + red[1][t] + red[2][t] + red[3][t]) * scale;
        float n2 = sv * sv;
#pragma unroll
        for (int m = 1; m < 16; m <<= 1) n2 += __shfl_xor(n2, m);
        float norm = sqrtf(n2);
        float scl  = n2 / (1.f + n2) / (norm + 1e-8f);
        float v = scl * sv;
        if (mode == 2)      out[bo * 16 + t] = v;
        else if (mode == 0) Vacc[bo * 16 + t] = v;
        else                Vacc[bo * 16 + t] += v;
    }
}

extern "C" void kernel_launch(void* const* d_in, const int* in_sizes, int n_in,
                              void* d_out, int out_size, void* d_ws, size_t ws_size,
                              hipStream_t stream) {
    const float* x = (const float*)d_in[0];   // (64, 8000, 8)
    const float* W = (const float*)d_in[1];   // (10, 8000, 16, 8)
    float* out = (float*)d_out;               // (64, 10, 16)

    char* ws = (char*)d_ws;
    float*  Vacc = (float*)ws;                                  // 40 KB
    __fp16* rec  = (__fp16*)(ws + VACC_F * sizeof(float));      // 28.7 MB f16 records
    __fp16* part = (__fp16*)(ws + VACC_F * sizeof(float) + REC_TOTAL_B);

    size_t head = VACC_F * sizeof(float) + REC_TOTAL_B;
    size_t avail = (ws_size > head) ? ws_size - head : 0;
    long slots = (long)(avail / (PART_H * sizeof(__fp16)));
    int grid = (int)((slots < NUNIT) ? slots : NUNIT);
    if (grid < 1) grid = 1;

    caps_prep<<<1500, 256, 0, stream>>>(W, x, rec);

    // iter 0: uniform c (0.1 folded into reduce scale)
    caps_pass<1><<<grid, 256, 0, stream>>>(rec, Vacc, part);
    caps_reduce<<<640, 256, 0, stream>>>(part, Vacc, out, grid, 0, 0.1f);
    // iter 1
    caps_pass<0><<<grid, 256, 0, stream>>>(rec, Vacc, part);
    caps_reduce<<<640, 256, 0, stream>>>(part, Vacc, out, grid, 1, 1.0f);
    // iter 2 (final): write v to out
    caps_pass<0><<<grid, 256, 0, stream>>>(rec, Vacc, part);
    caps_reduce<<<640, 256, 0, stream>>>(part, Vacc, out, grid, 2, 1.0f);
}

// Round 5
// 161.322 us; speedup vs baseline: 1.1578x; 1.1578x over previous
//
#include <hip/hip_runtime.h>
#include <hip/hip_fp16.h>
#include <math.h>

#define IN 8000
#define OC 10
#define NUNIT 1000              // 1000 units x 8 i
#define VACC_F (64 * OC * 16)   // 10240 floats
#define PART_H (64 * OC * 16)   // 10240 halfs per chunk (20 KB)

// per-unit f16 record: [8 il][10 o][16 d][8 e] (20480 B) then [8 il][64 b][8 e] (8192 B)
#define REC_B   28672
#define REC_H   14336
#define XOFF_B  20480
#define XOFF_H  10240
#define REC_TOTAL_B ((size_t)NUNIT * REC_B)   // 28,672,000

typedef __fp16 h2 __attribute__((ext_vector_type(2)));
typedef _Float16 half8 __attribute__((ext_vector_type(8)));
typedef float f32x16 __attribute__((ext_vector_type(16)));

__device__ __forceinline__ h2 asb(unsigned int v) { return __builtin_bit_cast(h2, v); }

__device__ __forceinline__ float dot2(h2 a, h2 b, float c) {
#if __has_builtin(__builtin_amdgcn_fdot2)
    return __builtin_amdgcn_fdot2(a, b, c, false);
#else
    return fmaf((float)a[0], (float)b[0], fmaf((float)a[1], (float)b[1], c));
#endif
}

__device__ __forceinline__ unsigned int pk_rn(float a, float b) {
    return __builtin_bit_cast(unsigned int, __float22half2_rn(make_float2(a, b)));
}

#define GLDS16(gp, lp) __builtin_amdgcn_global_load_lds(                      \
    (const __attribute__((address_space(1))) void*)(gp),                      \
    (__attribute__((address_space(3))) void*)(lp), 16, 0, 0)

// ---------------------------------------------------------------------------
// Prep: W (10,8000,16,8) f32 + x (64,8000,8) f32  ->  f16 unit records laid
// out exactly as the pass's LDS buffer, so staging is pure global_load_lds.
// Blocks [0,1250): W. granule = 8 halfs (one d-row); 1,280,000 granules, 4/thr.
// Blocks [1250,1500): x. wave w handles u = (blk-1250)*4+w, lane = b.
// ---------------------------------------------------------------------------
__global__ __launch_bounds__(256) void caps_prep(
    const float* __restrict__ W, const float* __restrict__ x,
    __fp16* __restrict__ rec)
{
    const int t   = threadIdx.x;
    const int blk = blockIdx.x;
    if (blk < 1250) {
        const int gt = blk * 256 + t;
#pragma unroll
        for (int k = 0; k < 4; ++k) {
            int g  = gt + k * 320000;
            int u  = g / 1280;
            int r  = g - u * 1280;
            int il = r / 160;
            int rr = r - il * 160;
            int o  = rr >> 4;
            int d  = rr & 15;
            const float* ip = W + ((size_t)o * IN + (size_t)(u * 8 + il)) * 128 + d * 8;
            float4 f0 = *(const float4*)(ip);
            float4 f1 = *(const float4*)(ip + 4);
            uint4 pk = make_uint4(pk_rn(f0.x, f0.y), pk_rn(f0.z, f0.w),
                                  pk_rn(f1.x, f1.y), pk_rn(f1.z, f1.w));
            *(uint4*)(rec + (size_t)u * REC_H + il * 1280 + o * 128 + d * 8) = pk;
        }
    } else {
        const int u    = (blk - 1250) * 4 + (t >> 6);
        const int lane = t & 63;           // = b
#pragma unroll
        for (int il = 0; il < 8; ++il) {
            const float* ip = x + ((size_t)lane * IN + (size_t)(u * 8 + il)) * 8;
            float4 f0 = *(const float4*)(ip);
            float4 f1 = *(const float4*)(ip + 4);
            uint4 pk = make_uint4(pk_rn(f0.x, f0.y), pk_rn(f0.z, f0.w),
                                  pk_rn(f1.x, f1.y), pk_rn(f1.z, f1.w));
            *(uint4*)(rec + (size_t)u * REC_H + XOFF_H + il * 512 + lane * 8) = pk;
        }
    }
}

// ---------------------------------------------------------------------------
// Kernel A (round-3 skeleton, verified): 256 thr (4 waves = 2 b-halves x
// 2 i-set halves), grid = 500, 2 units/block. Both units DMA'd into LDS
// up-front via global_load_lds; one __syncthreads (vmcnt(0) drain) makes
// both resident; compute runs barrier-free. New vs round 3: packed-f16
// routing accumulator (v_pk_fma_f16, round-4-verified numerics), max3
// softmax max, tree exp-sum.
// ---------------------------------------------------------------------------
template<int UNIFORM>
__global__ __launch_bounds__(256, 2) void caps_pass(
    const __fp16* __restrict__ rec, const float* __restrict__ Vacc,
    __fp16* __restrict__ part)
{
    __shared__ __align__(16) unsigned char sm[2 * REC_B];   // 57344 B
    __shared__ __align__(16) unsigned char zs[16];          // zero slot

    const int t    = threadIdx.x;
    const int w    = t >> 6;
    const int lane = t & 63;
    const int lo   = lane & 31;
    const int hi   = lane >> 5;
    const int bt   = w & 1;            // b-half: b in [bt*32, bt*32+32)
    const int ph   = w >> 1;           // i-set half (0/1)
    const int b    = bt * 32 + lo;

    if (t < 4) ((unsigned int*)zs)[t] = 0u;

    // cached v * log2e as f16 pairs matching this lane's C-row d pattern:
    // vh[o][0..3] = v[d], d = {0,1,2,3,8,9,10,11} + 4*hi
    h2 vh[10][4];
    if (!UNIFORM) {
        const float* vp = Vacc + (size_t)b * (OC * 16);
        const float L2E = 1.44269504f;
#pragma unroll
        for (int o = 0; o < OC; ++o) {
            float4 fa = *(const float4*)(vp + o * 16 + 4 * hi);
            float4 fb = *(const float4*)(vp + o * 16 + 8 + 4 * hi);
            vh[o][0] = asb(pk_rn(fa.x * L2E, fa.y * L2E));
            vh[o][1] = asb(pk_rn(fa.z * L2E, fa.w * L2E));
            vh[o][2] = asb(pk_rn(fb.x * L2E, fb.y * L2E));
            vh[o][3] = asb(pk_rn(fb.z * L2E, fb.w * L2E));
        }
    }

    // UNIFORM accumulator: f32 MFMA C-regs. Routing accumulator: packed f16.
    f32x16 acc[5];
    h2 acch[5][8];
    if (UNIFORM) {
#pragma unroll
        for (int op = 0; op < 5; ++op)
#pragma unroll
            for (int k = 0; k < 16; ++k) acc[op][k] = 0.f;
    } else {
#pragma unroll
        for (int op = 0; op < 5; ++op)
#pragma unroll
            for (int q = 0; q < 8; ++q) acch[op][q] = h2{(__fp16)0.f, (__fp16)0.f};
    }

    f32x16 zc;
#pragma unroll
    for (int k = 0; k < 16; ++k) zc[k] = 0.f;

    const int bid  = blockIdx.x;
    const int grid = gridDim.x;

    // staging: 28 chunks of 1 KiB per unit; wave w issues q = c*4+w
    auto issue = [&](int st, int bufi) {
        const char* g = (const char*)rec + (size_t)st * REC_B + (size_t)lane * 16;
        unsigned char* lb = sm + bufi * REC_B;
#pragma unroll
        for (int c = 0; c < 7; ++c) {
            const int q = c * 4 + w;
            GLDS16(g + q * 1024, lb + q * 1024);
        }
    };

    issue(bid, 0);
    if (bid + grid < NUNIT) issue(bid + grid, 1);
    __syncthreads();                 // drains vmcnt(0): both buffers resident

    int cur = 0;
    for (int st = bid; st < NUNIT; st += grid) {
        const unsigned char* buf = sm + cur * REC_B;

        if (UNIFORM) {
            // dense: 2 i's per MFMA along K (k-group = lane>>5 -> i')
#pragma unroll
            for (int ip = 0; ip < 2; ++ip) {
                const int il0 = ph * 4 + ip * 2;
                half8 xb = *(const half8*)(buf + XOFF_B + (il0 + hi) * 1024 + b * 16);
#pragma unroll
                for (int op = 0; op < 5; ++op) {
                    half8 av = *(const half8*)(buf + (il0 + hi) * 2560 + op * 512 + lo * 16);
                    acc[op] = __builtin_amdgcn_mfma_f32_32x32x16_f16(av, xb, acc[op], 0, 0, 0);
                }
            }
        } else {
#pragma unroll 1
            for (int u = 0; u < 4; ++u) {
                const int il = ph * 4 + u;
                // B operand: lanes<32 real x rows (k=e), lanes>=32 -> zero slot
                const unsigned char* xaddr = (lane < 32)
                    ? (buf + XOFF_B + il * 1024 + b * 16)
                    : (const unsigned char*)zs;
                half8 xb = *(const half8*)xaddr;

                h2 uh2[5][8];
                float lgf[10];
#pragma unroll
                for (int op = 0; op < 5; ++op) {
                    // A: lanes>=32 duplicate lanes 0-31 (k>=8 don't-care, B=0 there)
                    half8 av = *(const half8*)(buf + il * 2560 + op * 512 + lo * 16);
                    f32x16 C = __builtin_amdgcn_mfma_f32_32x32x16_f16(av, xb, zc, 0, 0, 0);
#pragma unroll
                    for (int q = 0; q < 8; ++q)
                        uh2[op][q] = __builtin_amdgcn_cvt_pkrtz(C[2 * q], C[2 * q + 1]);
                    float l0 = 0.f, l1 = 0.f;
#pragma unroll
                    for (int qq = 0; qq < 4; ++qq) {
                        l0 = dot2(uh2[op][qq],     vh[op * 2][qq],     l0);
                        l1 = dot2(uh2[op][4 + qq], vh[op * 2 + 1][qq], l1);
                    }
                    lgf[op * 2]     = l0;
                    lgf[op * 2 + 1] = l1;
                }
                // d-reduce: partner lane (l^32) holds the other 8 d's of each o
#pragma unroll
                for (int pp = 0; pp < 5; ++pp) {
                    h2 lp = asb(pk_rn(lgf[2 * pp], lgf[2 * pp + 1]));
                    int ob = __shfl_xor(__builtin_bit_cast(int, lp), 32);
                    h2 s2 = lp + __builtin_bit_cast(h2, ob);
                    lgf[2 * pp]     = (float)s2[0];
                    lgf[2 * pp + 1] = (float)s2[1];
                }
                // softmax over 10 o; max via fmax triples (v_max3_f32, T17)
                float m0 = fmaxf(fmaxf(lgf[0], lgf[1]), lgf[2]);
                float m1 = fmaxf(fmaxf(lgf[3], lgf[4]), lgf[5]);
                float m2 = fmaxf(fmaxf(lgf[6], lgf[7]), lgf[8]);
                float mx = fmaxf(fmaxf(m0, m1), fmaxf(m2, lgf[9]));
                float pe[10];
#pragma unroll
                for (int o = 0; o < OC; ++o)
                    pe[o] = __builtin_amdgcn_exp2f(lgf[o] - mx);
                // tree sum (shallow chain)
                float s01 = pe[0] + pe[1], s23 = pe[2] + pe[3];
                float s45 = pe[4] + pe[5], s67 = pe[6] + pe[7];
                float s89 = pe[8] + pe[9];
                float se = ((s01 + s23) + (s45 + s67)) + s89;
                float rs = __builtin_amdgcn_rcpf(se);
                // weighted accumulate, packed f16: acch += c ⊙ uh2 (pk_fma)
#pragma unroll
                for (int op = 0; op < 5; ++op) {
                    float c0 = pe[op * 2] * rs;
                    float c1 = pe[op * 2 + 1] * rs;
                    h2 ch0 = __builtin_amdgcn_cvt_pkrtz(c0, c0);
                    h2 ch1 = __builtin_amdgcn_cvt_pkrtz(c1, c1);
#pragma unroll
                    for (int q = 0; q < 4; ++q) {
                        acch[op][q]     = ch0 * uh2[op][q]     + acch[op][q];
                        acch[op][4 + q] = ch1 * uh2[op][4 + q] + acch[op][4 + q];
                    }
                }
            }
        }

        // grid<500 fallback only: refill the buffer just consumed.
        const int nxt = st + 2 * grid;
        if (nxt < NUNIT) {
            __syncthreads();         // everyone done reading buf[cur]
            issue(nxt, cur);
            __syncthreads();         // drain: refilled buffer resident
        }
        cur ^= 1;
    }

    // block reduce across the two ph-waves per bt; red aliases sm: [64][164] f32
    float* red = (float*)sm;
#pragma unroll 1
    for (int phase = 0; phase < 2; ++phase) {
        __syncthreads();
        if (ph == phase) {
#pragma unroll
            for (int op = 0; op < 5; ++op)
#pragma unroll
                for (int q = 0; q < 8; ++q) {
                    const int o  = op * 2 + (q >> 2);
                    const int d0 = 2 * (q & 1) + 8 * ((q >> 1) & 1) + 4 * hi;
                    float e0, e1;
                    if (UNIFORM) { e0 = acc[op][2 * q]; e1 = acc[op][2 * q + 1]; }
                    else         { e0 = (float)acch[op][q][0]; e1 = (float)acch[op][q][1]; }
                    float* p = &red[(size_t)b * 164 + o * 16 + d0];
                    if (phase == 0) {
                        *(float2*)p = make_float2(e0, e1);
                    } else {
                        float2 v2 = *(const float2*)p;
                        v2.x += e0; v2.y += e1;
                        *(float2*)p = v2;
                    }
                }
        }
    }
    __syncthreads();
    // flush partial as f16, transposed: part[bo][chunk][16]
    unsigned int* dst = (unsigned int*)part;
    for (int q = t; q < PART_H / 2; q += 256) {
        int bo = q >> 3;
        int u8 = q & 7;
        int bb = bo / 10;
        int oo = bo - bb * 10;
        float2 v2 = *(const float2*)&red[(size_t)bb * 164 + oo * 16 + u8 * 2];
        dst[(size_t)(bo * grid + bid) * 8 + u8] = pk_rn(v2.x, v2.y);
    }
}

// ---------------------------------------------------------------------------
// Kernel B: one block per (b,o). part is [bo][chunk][16] f16 -> coalesced.
// mode 0: Vacc =, mode 1: Vacc +=, mode 2: out =.
// ---------------------------------------------------------------------------
__global__ __launch_bounds__(256) void caps_reduce(
    const __fp16* __restrict__ part, float* __restrict__ Vacc,
    float* __restrict__ out, int nchunk, int mode, float scale)
{
    const int bo = blockIdx.x;      // b*10+o, [0,640)
    const int t  = threadIdx.x;
    const int d2 = t & 3;           // 4 d's: 4*d2..4*d2+3
    const int s  = t >> 2;          // 64 chunk slices

    const unsigned int* p32 = (const unsigned int*)part + (size_t)bo * nchunk * 8;
    float4 a = make_float4(0.f, 0.f, 0.f, 0.f);
    for (int c = s; c < nchunk; c += 64) {
        uint2 v = *(const uint2*)(p32 + (size_t)c * 8 + d2 * 2);
        h2 lov = asb(v.x), hiv = asb(v.y);
        a.x += (float)lov[0]; a.y += (float)lov[1];
        a.z += (float)hiv[0]; a.w += (float)hiv[1];
    }
#pragma unroll
    for (int m = 4; m <= 32; m <<= 1) {
        a.x += __shfl_xor(a.x, m); a.y += __shfl_xor(a.y, m);
        a.z += __shfl_xor(a.z, m); a.w += __shfl_xor(a.w, m);
    }
    __shared__ float red[4][16];
    const int wv = t >> 6;
    if ((t & 63) < 4) {
        red[wv][d2 * 4 + 0] = a.x; red[wv][d2 * 4 + 1] = a.y;
        red[wv][d2 * 4 + 2] = a.z; red[wv][d2 * 4 + 3] = a.w;
    }
    __syncthreads();
    if (t < 16) {
        float sv = (red[0][t] + red[1][t] + red[2][t] + red[3][t]) * scale;
        float n2 = sv * sv;
#pragma unroll
        for (int m = 1; m < 16; m <<= 1) n2 += __shfl_xor(n2, m);
        float norm = sqrtf(n2);
        float scl  = n2 / (1.f + n2) / (norm + 1e-8f);
        float v = scl * sv;
        if (mode == 2)      out[bo * 16 + t] = v;
        else if (mode == 0) Vacc[bo * 16 + t] = v;
        else                Vacc[bo * 16 + t] += v;
    }
}

extern "C" void kernel_launch(void* const* d_in, const int* in_sizes, int n_in,
                              void* d_out, int out_size, void* d_ws, size_t ws_size,
                              hipStream_t stream) {
    const float* x = (const float*)d_in[0];   // (64, 8000, 8)
    const float* W = (const float*)d_in[1];   // (10, 8000, 16, 8)
    float* out = (float*)d_out;               // (64, 10, 16)

    char* ws = (char*)d_ws;
    float*  Vacc = (float*)ws;                                  // 40 KB
    __fp16* rec  = (__fp16*)(ws + VACC_F * sizeof(float));      // 28.7 MB f16 records
    __fp16* part = (__fp16*)(ws + VACC_F * sizeof(float) + REC_TOTAL_B);

    size_t head = VACC_F * sizeof(float) + REC_TOTAL_B;
    size_t avail = (ws_size > head) ? ws_size - head : 0;
    long slots = (long)(avail / (PART_H * sizeof(__fp16)));
    int grid = (int)((slots < 500) ? slots : 500);
    if (grid < 1) grid = 1;

    caps_prep<<<1500, 256, 0, stream>>>(W, x, rec);

    // iter 0: uniform c (0.1 folded into reduce scale)
    caps_pass<1><<<grid, 256, 0, stream>>>(rec, Vacc, part);
    caps_reduce<<<640, 256, 0, stream>>>(part, Vacc, out, grid, 0, 0.1f);
    // iter 1
    caps_pass<0><<<grid, 256, 0, stream>>>(rec, Vacc, part);
    caps_reduce<<<640, 256, 0, stream>>>(part, Vacc, out, grid, 1, 1.0f);
    // iter 2 (final): write v to out
    caps_pass<0><<<grid, 256, 0, stream>>>(rec, Vacc, part);
    caps_reduce<<<640, 256, 0, stream>>>(part, Vacc, out, grid, 2, 1.0f);
}